// Round 5
// baseline (260.081 us; speedup 1.0000x reference)
//
#include <hip/hip_runtime.h>
#include <hip/hip_bf16.h>

// Problem constants
#define B_      64
#define C_      3
#define H_      224
#define W_      224
#define P_      (H_*W_)      // 50176 pixels per image
#define S_      196          // MAX_SEGMENTS
#define MAXPIX  400
#define E_      768          // EMBED
#define K_      1200         // C*MAXPIX
#define KP_     1216         // K padded to multiple of 32
#define CHUNK_  512
#define NCH_    (P_/CHUNK_)  // 98 chunks per image
#define M_      (B_*S_)      // 12544 GEMM rows
#define QPR_    304          // quads per row: 300 data (3ch x 100) + 4 pad
#define GQ_GRID 4096

typedef __attribute__((ext_vector_type(8))) short short8;
typedef __attribute__((ext_vector_type(4))) float f32x4;

__device__ inline unsigned short f2bf(float f) {
  union { float f; unsigned int u; } x; x.f = f;
  return (unsigned short)((x.u + 0x7fffu + ((x.u >> 16) & 1u)) >> 16);
}

// chunked XCD swizzle, nwg % 8 == 0: XCD k owns a contiguous span of nwg/8 blocks
__device__ inline int xcd_chunk(int wg, int nwg) {
  int q = nwg >> 3;
  return (wg & 7) * q + (wg >> 3);
}

// ---------------- W fp32 -> bf16 with K-padding ----------------
__global__ void wconv_k(const float* __restrict__ Wf, unsigned short* __restrict__ Wb) {
  int idx = blockIdx.x * 256 + threadIdx.x;     // 0 .. E_*KP_ (exact grid)
  int e = idx / KP_, k = idx - e * KP_;
  float v = (k < K_) ? Wf[e * K_ + k] : 0.f;
  Wb[idx] = f2bf(v);
}

// ---------------- per-chunk rank + histogram ----------------
__global__ __launch_bounds__(512) void rank_k(const int* __restrict__ seg,
                                              int* __restrict__ hist,
                                              unsigned short* __restrict__ rloc) {
  int b = blockIdx.x / NCH_, ch = blockIdx.x % NCH_;
  int tid = threadIdx.x, wave = tid >> 6, lane = tid & 63;
  int p = ch * CHUNK_ + tid;
  int s = seg[b * P_ + p];

  __shared__ int lhist[8][S_];
  for (int i = tid; i < 8 * S_; i += 512) ((int*)lhist)[i] = 0;
  __syncthreads();

  // count earlier lanes in this wave with the same segment id (stable raster rank)
  int r = 0;
  #pragma unroll 1
  for (int j = 0; j < 64; ++j) {
    int sj = __shfl(s, j);
    r += (j < lane && sj == s) ? 1 : 0;
  }
  atomicAdd(&lhist[wave][s], 1);
  __syncthreads();

  int off = 0;
  for (int w2 = 0; w2 < wave; ++w2) off += lhist[w2][s];
  rloc[b * P_ + p] = (unsigned short)(off + r);

  if (tid < S_) {
    int t = 0;
    #pragma unroll
    for (int w2 = 0; w2 < 8; ++w2) t += lhist[w2][tid];
    hist[(b * NCH_ + ch) * S_ + tid] = t;
  }
}

// ---------------- parallel exclusive prefix over chunks per (b, s) ----------------
__global__ __launch_bounds__(128) void prefix_k(int* __restrict__ hist, int* __restrict__ cnts) {
  int b = blockIdx.x / S_, s = blockIdx.x % S_;
  int t = threadIdx.x;
  __shared__ int sc[128];
  int v = (t < NCH_) ? hist[(b * NCH_ + t) * S_ + s] : 0;
  sc[t] = v;
  __syncthreads();
  #pragma unroll
  for (int off = 1; off < 128; off <<= 1) {
    int x = (t >= off) ? sc[t - off] : 0;
    __syncthreads();
    sc[t] += x;
    __syncthreads();
  }
  if (t < NCH_) hist[(b * NCH_ + t) * S_ + s] = sc[t] - v;   // exclusive
  if (t == NCH_ - 1) {
    int tot = sc[t];
    cnts[b * S_ + s] = tot < MAXPIX ? tot : MAXPIX;
  }
}

// ---------------- scatter pixel ids -> inv[b][s][rank] (uint16) ----------------
__global__ __launch_bounds__(256) void scatter_inv_k(const int* __restrict__ seg,
                                                     const int* __restrict__ starts,
                                                     const unsigned short* __restrict__ rloc,
                                                     unsigned short* __restrict__ inv) {
  int wg = xcd_chunk(blockIdx.x, B_ * (P_ / 256));   // contiguous pixel span per XCD
  int b = wg / (P_ / 256);
  int p = (wg % (P_ / 256)) * 256 + threadIdx.x;
  int s = seg[b * P_ + p];
  int rank = starts[(b * NCH_ + (p >> 9)) * S_ + s] + rloc[b * P_ + p];
  if (rank < MAXPIX)
    inv[(b * S_ + s) * MAXPIX + rank] = (unsigned short)p;
}

// ---------------- gather img -> feats rows (quad-vectorized, high ILP) ----------------
// work unit = one quad: 4 consecutive ranks of one (row, channel), or 4 pad elems.
// 1 ushort4 inv load -> 4 independent img gathers -> 1 packed 8B store.
__global__ __launch_bounds__(256) void gather_k(const float* __restrict__ img,
                                                const unsigned short* __restrict__ inv,
                                                const int* __restrict__ cnts,
                                                unsigned short* __restrict__ feats) {
  const int nq = M_ * QPR_;
  int blk = xcd_chunk(blockIdx.x, GQ_GRID);
  for (int q = blk * 256 + threadIdx.x; q < nq; q += GQ_GRID * 256) {
    int row = q / QPR_;
    int qi = q - row * QPR_;
    unsigned short* frow = feats + (size_t)row * KP_;
    if (qi >= 300) {
      *(ushort4*)&frow[K_ + ((qi - 300) << 2)] = make_ushort4(0, 0, 0, 0);
      continue;
    }
    int c = qi / 100;
    int r4 = (qi - c * 100) << 2;
    int b = row / S_;
    int cnt = cnts[row];
    ushort4 pq = *(const ushort4*)&inv[(size_t)row * MAXPIX + r4];
    const float* ic = img + ((size_t)b * C_ + c) * P_;
    ushort4 o;
    o.x = (r4 + 0 < cnt) ? f2bf(ic[pq.x]) : (unsigned short)0;
    o.y = (r4 + 1 < cnt) ? f2bf(ic[pq.y]) : (unsigned short)0;
    o.z = (r4 + 2 < cnt) ? f2bf(ic[pq.z]) : (unsigned short)0;
    o.w = (r4 + 3 < cnt) ? f2bf(ic[pq.w]) : (unsigned short)0;
    *(ushort4*)&frow[c * MAXPIX + r4] = o;
  }
}

// ---------------- bf16 MFMA GEMM: out[M][E] = feats[M][KP] * Wb[E][KP]^T + bias ----------------
__global__ __launch_bounds__(256) void gemm_k(const unsigned short* __restrict__ A,
                                              const unsigned short* __restrict__ Bw,
                                              const float* __restrict__ bias,
                                              float* __restrict__ out) {
  // bijective chunked swizzle (m204): nwg=588, q=73, r=4 -> blocks sharing an
  // A-panel (6 consecutive) land on one XCD
  int bid;
  {
    int wg = blockIdx.x, q = 588 / 8, r = 588 % 8;
    int xcd = wg % 8, idx = wg / 8;
    bid = (xcd < r) ? xcd * (q + 1) + idx : r * (q + 1) + (xcd - r) * q + idx;
  }
  const int nb = bid % (E_ / 128);   // 0..5
  const int mb = bid / (E_ / 128);   // 0..97
  const int tid = threadIdx.x;
  const int w = tid >> 6, l = tid & 63;
  const int wr = w >> 1, wc = w & 1;

  __shared__ __align__(16) unsigned short As[128 * 32];
  __shared__ __align__(16) unsigned short Bs[128 * 32];

  f32x4 acc[4][4] = {};

  const int lrow = l >> 2;        // 0..15
  const int lcol = (l & 3) * 8;   // element offset within 32-wide K slice
  const int kk = (l >> 4) * 8;    // fragment K offset

  for (int k0 = 0; k0 < KP_; k0 += 32) {
    #pragma unroll
    for (int q = 0; q < 2; ++q) {
      int r = (w * 2 + q) * 16 + lrow;
      const unsigned short* ga = A + (size_t)(mb * 128 + r) * KP_ + k0 + lcol;
      __builtin_amdgcn_global_load_lds((const __attribute__((address_space(1))) unsigned int*)ga,
                                       (__attribute__((address_space(3))) unsigned int*)&As[(w * 2 + q) * 512],
                                       16, 0, 0);
      const unsigned short* gb = Bw + (size_t)(nb * 128 + r) * KP_ + k0 + lcol;
      __builtin_amdgcn_global_load_lds((const __attribute__((address_space(1))) unsigned int*)gb,
                                       (__attribute__((address_space(3))) unsigned int*)&Bs[(w * 2 + q) * 512],
                                       16, 0, 0);
    }
    __syncthreads();

    short8 af[4], bf[4];
    #pragma unroll
    for (int mi = 0; mi < 4; ++mi)
      af[mi] = *(const short8*)&As[(wr * 64 + mi * 16 + (l & 15)) * 32 + kk];
    #pragma unroll
    for (int ni = 0; ni < 4; ++ni)
      bf[ni] = *(const short8*)&Bs[(wc * 64 + ni * 16 + (l & 15)) * 32 + kk];
    #pragma unroll
    for (int mi = 0; mi < 4; ++mi)
      #pragma unroll
      for (int ni = 0; ni < 4; ++ni)
        acc[mi][ni] = __builtin_amdgcn_mfma_f32_16x16x32_bf16(af[mi], bf[ni], acc[mi][ni], 0, 0, 0);
    __syncthreads();
  }

  // epilogue: C/D layout col = lane&15, row = (lane>>4)*4 + reg  [verified m89/m91]
  const int r0 = (l >> 4) * 4;
  const int c0 = l & 15;
  #pragma unroll
  for (int mi = 0; mi < 4; ++mi) {
    #pragma unroll
    for (int ni = 0; ni < 4; ++ni) {
      int col = nb * 128 + wc * 64 + ni * 16 + c0;
      float bv = bias[col];
      int row = mb * 128 + wr * 64 + mi * 16 + r0;
      #pragma unroll
      for (int r = 0; r < 4; ++r)
        out[(size_t)(row + r) * E_ + col] = acc[mi][ni][r] + bv;
    }
  }
}

extern "C" void kernel_launch(void* const* d_in, const int* in_sizes, int n_in,
                              void* d_out, int out_size, void* d_ws, size_t ws_size,
                              hipStream_t stream) {
  const float* img  = (const float*)d_in[0];   // [64,3,224,224]
  const int*   seg  = (const int*)d_in[1];     // [64,224,224]
  const float* Wf   = (const float*)d_in[2];   // [768,1200]
  const float* bias = (const float*)d_in[3];   // [768]
  float* out = (float*)d_out;                  // [64,196,768]

  // workspace layout with lifetime overlap (total 42.5 MB):
  //   [Wb 1.87M][inv 10.04M][cnts 0.05M][feats 30.5M]
  //   rloc/hist live inside the feats region (dead before gather_k writes feats)
  constexpr size_t WB_BYTES    = (size_t)E_ * KP_ * 2;        //  1,867,776
  constexpr size_t INV_BYTES   = (size_t)M_ * MAXPIX * 2;     // 10,035,200
  constexpr size_t CNT_BYTES   = (size_t)M_ * 4;              //     50,176
  constexpr size_t RLOC_BYTES  = (size_t)B_ * P_ * 2;         //  6,422,528
  char* ws = (char*)d_ws;
  unsigned short* Wb    = (unsigned short*)ws;
  unsigned short* inv   = (unsigned short*)(ws + WB_BYTES);
  int*            cnts  = (int*)(ws + WB_BYTES + INV_BYTES);
  unsigned short* feats = (unsigned short*)(ws + WB_BYTES + INV_BYTES + CNT_BYTES);
  unsigned short* rloc  = feats;                                      // overlaid
  int*            hist  = (int*)((char*)feats + RLOC_BYTES);          // overlaid

  wconv_k<<<(E_ * KP_) / 256, 256, 0, stream>>>(Wf, Wb);
  rank_k<<<B_ * NCH_, 512, 0, stream>>>(seg, hist, rloc);
  prefix_k<<<B_ * S_, 128, 0, stream>>>(hist, cnts);
  scatter_inv_k<<<B_ * (P_ / 256), 256, 0, stream>>>(seg, hist, rloc, inv);
  gather_k<<<GQ_GRID, 256, 0, stream>>>(img, inv, cnts, feats);
  gemm_k<<<(M_ / 128) * (E_ / 128), 256, 0, stream>>>(feats, Wb, bias, out);
}